// Round 2
// baseline (70.947 us; speedup 1.0000x reference)
//
#include <hip/hip_runtime.h>
#include <math.h>

#define QROWS 256
#define RT    28528

// Grid: block 0 = q section (256 rows).
// Blocks 1..120   = k section, one block per 256-row chunk of each group.
// Blocks 121..240 = v section, same layout.
// chunk counts per group: ceil(R(g)/256) with R = {63,143,255,399,575,783,
// 1023,1295,1599,1935,2303,2703,3135,3599,4095,4623} -> sums to 120.
#define NBLOCKS 241

__global__ __launch_bounds__(256) void head_kernel(
    const float* __restrict__ x,   // (1,16,16,16)
    const float* __restrict__ Wq,  // (16,16)
    const float* __restrict__ Wk,  // (16,16,16)
    const float* __restrict__ bk,  // (16,16)
    const float* __restrict__ Wv,  // (16,16,16)
    const float* __restrict__ bv,  // (16,16)
    float* __restrict__ out)       // (57312,16)
{
    __shared__ float sx[4096];
    __shared__ float sW[256];
    __shared__ float sb[16];

    const int OFF[17] = {0, 63, 206, 461, 860, 1435, 2218, 3241, 4536, 6135,
                         8070, 10373, 13076, 16211, 19810, 23905, 28528};

    const int tid = threadIdx.x;
    const int b = blockIdx.x;

    // ---- block -> (section, group, chunk) : block-uniform scalar scan ----
    int g = 0, chunk = 0, sec = 0;
    const bool isq = (b == 0);
    if (!isq) {
        int bb = b - 1;
        if (bb >= 120) { sec = 1; bb -= 120; }
        for (int gg = 0; gg < 16; ++gg) {
            const int nc = (OFF[gg + 1] - OFF[gg] + 255) >> 8;
            if (bb < nc) { g = gg; chunk = bb; break; }
            bb -= nc;
        }
    }
    const int T = isq ? 16 : (g + 1);   // prefix length; x channels used are < T

    // ---- stage: x prefix (T*256 floats), one 16x16 weight, 16 biases ----
    for (int it = 0; it < T; ++it) {
        const int idx = tid + (it << 8);
        sx[idx] = x[idx];
    }
    if (isq) {
        sW[tid] = Wq[tid];
        if (tid < 16) sb[tid] = 0.0f;
    } else {
        sW[tid] = ((sec ? Wv : Wk) + g * 256)[tid];
        if (tid < 16) sb[tid] = (sec ? bv : bk)[g * 16 + tid];
    }
    __syncthreads();

    // ---- per-thread row decode ----
    int n, c, row;
    bool active = true;

    if (isq) {
        row = tid;
        n = tid >> 4;
        c = tid & 15;
    } else {
        const int Rg = OFF[g + 1] - OFF[g];
        int pos = (chunk << 8) + tid;
        if (pos >= Rg) { active = false; pos = 0; }
        row = QROWS + sec * RT + OFF[g] + pos;

        const int L = (T + 1) * (T + 1);
        int j, p;
        if (pos < L - 1) { j = 0; p = pos; }
        else             { j = (pos + 1) / L; p = (pos + 1) - j * L; }

        int timev, pat;
        if (p == 0) {
            timev = T - 1; pat = j;             // header entry (T-1, j)
        } else {
            const int qq = p - 1 + ((j == 0) ? 1 : 0); // j==0: skip (i=2,l=0)
            const int v = qq + 1;                      // generic position + 1
            int s = (int)sqrtf((float)v);
            if (s * s > v) --s;
            if ((s + 1) * (s + 1) <= v) ++s;           // s = floor(sqrt(v))
            const int i = s + 1;                       // block index (2..T+1)
            const int m = v - s * s;                   // position within block
            timev = T + 1 - i;
            int cm = i + j - 16; if (cm < 0) cm = 0;   // # of k=-1 entries
            if (m < cm) {
                pat = m;                               // k=-1 band
            } else {
                const int m2 = m - cm;
                const int lo0 = (1 - i > -j) ? (1 - i) : (-j);
                const int hi0 = (i - 1 < 15 - j) ? (i - 1) : (15 - j);
                const int c0 = hi0 - lo0 + 1;
                if (m2 < c0) pat = j + lo0 + m2;       // k=0 band
                else         pat = j + 17 - i + (m2 - c0); // k=+1 band
            }
        }
        // raw-reshape scrambling: flat F over (time,pat) -> (patch n, chan c)
        const int F = timev * 16 + pat;
        n = F / T;
        c = F - n * T;
    }

    // ---- gather 16 pixels of patch n, channel c ----
    const int base = c * 256 + ((n >> 2) << 6) + ((n & 3) << 2);
    float xr[16];
    #pragma unroll
    for (int pr = 0; pr < 4; ++pr) {
        const float4 v4 = *(const float4*)&sx[base + pr * 16];
        xr[pr * 4 + 0] = v4.x; xr[pr * 4 + 1] = v4.y;
        xr[pr * 4 + 2] = v4.z; xr[pr * 4 + 3] = v4.w;
    }

    // ---- 16x16 mat-vec + bias (weight reads are wave-uniform broadcasts) ----
    float o[16];
    #pragma unroll
    for (int e = 0; e < 16; ++e) {
        float acc = sb[e];
        #pragma unroll
        for (int q = 0; q < 16; ++q) acc += xr[q] * sW[e * 16 + q];
        o[e] = acc;
    }

    if (active) {
        float4* op = (float4*)(out + (size_t)row * 16);
        op[0] = *(float4*)&o[0];
        op[1] = *(float4*)&o[4];
        op[2] = *(float4*)&o[8];
        op[3] = *(float4*)&o[12];
    }
}

extern "C" void kernel_launch(void* const* d_in, const int* in_sizes, int n_in,
                              void* d_out, int out_size, void* d_ws, size_t ws_size,
                              hipStream_t stream) {
    (void)in_sizes; (void)n_in; (void)d_ws; (void)ws_size; (void)out_size;
    const float* x  = (const float*)d_in[0];
    const float* Wq = (const float*)d_in[1];
    const float* Wk = (const float*)d_in[2];
    const float* bk = (const float*)d_in[3];
    const float* Wv = (const float*)d_in[4];
    const float* bv = (const float*)d_in[5];
    float* out = (float*)d_out;
    head_kernel<<<NBLOCKS, 256, 0, stream>>>(x, Wq, Wk, bk, Wv, bv, out);
}